// Round 1
// baseline (1205.621 us; speedup 1.0000x reference)
//
#include <hip/hip_runtime.h>
#include <stdint.h>

#define Bb   16
#define INn  8192
#define Cc   64
#define Aa   512
#define Nn   512
#define OUTo 1024
#define Tt   32

// ---------------------------------------------------------------------------
// Precompute the 32-cycle spike schedule per (b, i) as a 32-bit mask.
// Replicates _uniform_spikes in fp32 exactly: rintf == round-half-even,
// fmodf is exact for positive args (matches np.mod), floorf/divide in fp32.
// ---------------------------------------------------------------------------
__global__ void spike_kernel(const float* __restrict__ x,
                             uint32_t* __restrict__ spk) {
    int idx = blockIdx.x * 256 + threadIdx.x;
    if (idx >= Bb * INn) return;
    float xv = x[idx];
    float nf = rintf(xv * 32.0f);
    int nspk = (int)nf;
    uint32_t m;
    if (nspk >= 32) {
        m = 0xFFFFFFFFu;
    } else if (nspk <= 0) {
        m = 0u;
    } else {
        float spacing = 32.0f / nf;   // fp32 division, matches reference
        m = 0u;
        #pragma unroll
        for (int t = 0; t < 32; ++t) {
            float ct = (float)t;
            bool fire = (floorf(ct / spacing) < nf) &&
                        (floorf(fmodf(ct, spacing)) == 0.0f);
            if (fire) m |= (1u << t);
        }
    }
    spk[idx] = m;
}

// ---------------------------------------------------------------------------
// One simulation cycle. Grid: (C, 4) blocks of 256 threads.
// Block (c, chunk): computes memb[c, :, chunk*128 .. chunk*128+127].
// Thread tid: n = chunk*128 + (tid & 127), batches bh*8 .. bh*8+7 (bh = tid>>7).
// Signals staged in LDS as sig[a][b] (fp32 0/1). Accumulation over a is
// strictly sequential in 'a' per (n,b) accumulator to match np einsum order.
// buf words: bit t = fired at cycle t. Reader of bit t-1 vs writer of bit t
// on the same word is race-free (32-bit store atomicity, disjoint bits).
// ---------------------------------------------------------------------------
__global__ __launch_bounds__(256) void cycle_kernel(
        const float* __restrict__ W,
        const float* __restrict__ thr,
        const int* __restrict__ src_core,
        const int* __restrict__ src_index,
        const uint32_t* __restrict__ spk,
        uint32_t* __restrict__ buf,
        float* __restrict__ memb,
        int t) {
    const int c   = blockIdx.x;
    const int tid = threadIdx.x;
    const int nl  = tid & 127;
    const int bh  = tid >> 7;           // 0 or 1 -> batches 0-7 / 8-15
    const int n   = blockIdx.y * 128 + nl;

    __shared__ float sig[Aa * Bb];      // [a][b]

    const int base = c * Aa;
    for (int idx = tid; idx < Aa * Bb; idx += 256) {
        int a = idx >> 4;
        int b = idx & 15;
        int sc = src_core[base + a];
        int si = src_index[base + a];
        uint32_t bit;
        if (sc < 0) {
            bit = (spk[b * INn + si] >> t) & 1u;
        } else {
            bit = (t > 0) ? ((buf[(sc * Bb + b) * Nn + si] >> (t - 1)) & 1u)
                          : 0u;
        }
        sig[a * Bb + b] = (float)bit;
    }
    __syncthreads();

    float acc[8];
    #pragma unroll
    for (int j = 0; j < 8; ++j) acc[j] = 0.0f;

    const float* wrow = W + (size_t)(c * Nn + n) * Aa;
    const int sb = bh * 8;

    for (int a0 = 0; a0 < Aa; a0 += 4) {
        float4 w4 = *(const float4*)(wrow + a0);
        float4 s00 = *(const float4*)(&sig[(a0 + 0) * Bb + sb]);
        float4 s01 = *(const float4*)(&sig[(a0 + 0) * Bb + sb + 4]);
        float4 s10 = *(const float4*)(&sig[(a0 + 1) * Bb + sb]);
        float4 s11 = *(const float4*)(&sig[(a0 + 1) * Bb + sb + 4]);
        float4 s20 = *(const float4*)(&sig[(a0 + 2) * Bb + sb]);
        float4 s21 = *(const float4*)(&sig[(a0 + 2) * Bb + sb + 4]);
        float4 s30 = *(const float4*)(&sig[(a0 + 3) * Bb + sb]);
        float4 s31 = *(const float4*)(&sig[(a0 + 3) * Bb + sb + 4]);
        // a0 + 0
        acc[0] += w4.x * s00.x; acc[1] += w4.x * s00.y;
        acc[2] += w4.x * s00.z; acc[3] += w4.x * s00.w;
        acc[4] += w4.x * s01.x; acc[5] += w4.x * s01.y;
        acc[6] += w4.x * s01.z; acc[7] += w4.x * s01.w;
        // a0 + 1
        acc[0] += w4.y * s10.x; acc[1] += w4.y * s10.y;
        acc[2] += w4.y * s10.z; acc[3] += w4.y * s10.w;
        acc[4] += w4.y * s11.x; acc[5] += w4.y * s11.y;
        acc[6] += w4.y * s11.z; acc[7] += w4.y * s11.w;
        // a0 + 2
        acc[0] += w4.z * s20.x; acc[1] += w4.z * s20.y;
        acc[2] += w4.z * s20.z; acc[3] += w4.z * s20.w;
        acc[4] += w4.z * s21.x; acc[5] += w4.z * s21.y;
        acc[6] += w4.z * s21.z; acc[7] += w4.z * s21.w;
        // a0 + 3
        acc[0] += w4.w * s30.x; acc[1] += w4.w * s30.y;
        acc[2] += w4.w * s30.z; acc[3] += w4.w * s30.w;
        acc[4] += w4.w * s31.x; acc[5] += w4.w * s31.y;
        acc[6] += w4.w * s31.z; acc[7] += w4.w * s31.w;
    }

    const float th = thr[c];
    #pragma unroll
    for (int j = 0; j < 8; ++j) {
        int b = sb + j;
        size_t off = (size_t)(c * Bb + b) * Nn + n;
        float m = memb[off] + acc[j];     // single add, like reference
        uint32_t wd = buf[off];
        if (th < m) {                      // strict <, like reference
            m -= th;
            wd |= (1u << t);
        }
        memb[off] = m;
        buf[off] = wd;
    }
}

// ---------------------------------------------------------------------------
// out[b, o] = popcount(buf[oc[o], b, oi[o]]) = sum over cycles of fire bit.
// ---------------------------------------------------------------------------
__global__ void out_kernel(const uint32_t* __restrict__ buf,
                           const int* __restrict__ oc,
                           const int* __restrict__ oi,
                           float* __restrict__ out) {
    int idx = blockIdx.x * 256 + threadIdx.x;
    if (idx >= Bb * OUTo) return;
    int b = idx / OUTo;
    int o = idx - b * OUTo;
    uint32_t wd = buf[(oc[o] * Bb + b) * Nn + oi[o]];
    out[idx] = (float)__popc(wd);
}

extern "C" void kernel_launch(void* const* d_in, const int* in_sizes, int n_in,
                              void* d_out, int out_size, void* d_ws,
                              size_t ws_size, hipStream_t stream) {
    const float* x         = (const float*)d_in[0];
    const float* W         = (const float*)d_in[1];
    const float* thr       = (const float*)d_in[2];
    const int*   src_core  = (const int*)d_in[3];
    const int*   src_index = (const int*)d_in[4];
    const int*   osc       = (const int*)d_in[5];
    const int*   osi       = (const int*)d_in[6];
    float* out = (float*)d_out;

    // ws layout: spk [B*IN u32] | buf [C*B*N u32] | memb [C*B*N f32]
    uint32_t* spk  = (uint32_t*)d_ws;
    uint32_t* buf  = (uint32_t*)((char*)d_ws + (size_t)Bb * INn * 4);
    float*    memb = (float*)((char*)d_ws + (size_t)Bb * INn * 4
                                          + (size_t)Cc * Bb * Nn * 4);

    // zero buf + memb (must re-init every call; ws poisoned once by harness)
    hipMemsetAsync(buf, 0, (size_t)Cc * Bb * Nn * 4 * 2, stream);

    spike_kernel<<<dim3((Bb * INn) / 256), 256, 0, stream>>>(x, spk);

    for (int t = 0; t < Tt; ++t) {
        cycle_kernel<<<dim3(Cc, 4), 256, 0, stream>>>(
            W, thr, src_core, src_index, spk, buf, memb, t);
    }

    out_kernel<<<dim3((Bb * OUTo + 255) / 256), 256, 0, stream>>>(
        buf, osc, osi, out);
}